// Round 3
// baseline (505.990 us; speedup 1.0000x reference)
//
#include <hip/hip_runtime.h>
#include <stdint.h>

typedef unsigned short u16;

#define NROWS    16384
#define C_DIM    1024
#define DFF      4096
#define TILE_UP  1024
#define TILE_OUT 256
#define LDA      40      // padded bf16 LDS row stride (80 B: breaks pow2 banking, keeps 16B align)

using short8 = __attribute__((ext_vector_type(8))) short;
using f32x4  = __attribute__((ext_vector_type(4))) float;

// pack two f32 -> two bf16 (RTZ truncation) in one v_perm_b32
__device__ __forceinline__ unsigned pk2(float lo, float hi) {
  union { float f; unsigned u; } L, H; L.f = lo; H.f = hi;
  return __builtin_amdgcn_perm(H.u, L.u, 0x07060302u);
}
// single f32 -> bf16 RNE
__device__ __forceinline__ u16 f2bf(float f) {
  union { float f; unsigned u; } v; v.f = f;
  return (u16)((v.u + 0x7FFFu + ((v.u >> 16) & 1u)) >> 16);
}

__global__ void k_zero(int* __restrict__ cnt) {
  if (threadIdx.x < 4) cnt[threadIdx.x] = 0;
}

// one wave per row: logits = x . W_gate^T + b_gate (all f32), argmax -> bucket + one-hot
__global__ void k_gate(const float* __restrict__ x, const float* __restrict__ wg,
                       const float* __restrict__ bg, float* __restrict__ gate_out,
                       int* __restrict__ cnt, int* __restrict__ rowlist) {
  const int w = threadIdx.x >> 6, lane = threadIdx.x & 63;
  const int n = (blockIdx.x << 2) + w;
  const float4* xr = (const float4*)(x + (size_t)n * C_DIM);
  float s[4] = {0.f, 0.f, 0.f, 0.f};
  for (int c4 = lane; c4 < 256; c4 += 64) {
    float4 xv = xr[c4];
#pragma unroll
    for (int j = 0; j < 4; ++j) {
      float4 wv = ((const float4*)(wg + j * C_DIM))[c4];
      s[j] += xv.x * wv.x + xv.y * wv.y + xv.z * wv.z + xv.w * wv.w;
    }
  }
#pragma unroll
  for (int j = 0; j < 4; ++j) {
#pragma unroll
    for (int off = 32; off > 0; off >>= 1) s[j] += __shfl_down(s[j], off, 64);
  }
  if (lane == 0) {
    int g = 0; float best = s[0] + bg[0];
#pragma unroll
    for (int j = 1; j < 4; ++j) {
      float v = s[j] + bg[j];
      if (v > best) { best = v; g = j; }   // strict > == first max, matches np.argmax
    }
    int pos = atomicAdd(&cnt[g], 1);
    rowlist[g * NROWS + pos] = n;
    float4 oh;
    oh.x = (g == 0) ? 1.f : 0.f;
    oh.y = (g == 1) ? 1.f : 0.f;
    oh.z = (g == 2) ? 1.f : 0.f;
    oh.w = (g == 3) ? 1.f : 0.f;
    *(float4*)(gate_out + (size_t)n * 4) = oh;
  }
}

// grouped GEMM: hid_bf16[n, 0:1024] = relu(x[n] @ W_up[g*1024+:, :]^T + b_up)
// hid row n lives in the FIRST 2048 bytes of out's f32 row n (row-aligned aliasing).
// 128x128 tile, BK=32, 256 thr = 4 waves (64x64 each). f32 global -> bf16 LDS on the fly.
__global__ void k_up(const float* __restrict__ X, const float* __restrict__ Wup,
                     const float* __restrict__ bup, u16* __restrict__ hid16,
                     const int* __restrict__ cnt, const int* __restrict__ rowlist) {
  const int g = blockIdx.z;
  const int count = cnt[g];
  const int m_base = blockIdx.y << 7;
  if (m_base >= count) return;
  const int nb = blockIdx.x;  // 0..7

  __shared__ __align__(16) u16 lA[128 * LDA];
  __shared__ __align__(16) u16 lB[128 * LDA];
  __shared__ int lrow[128];

  const int tid = threadIdx.x;
  if (tid < 128) {
    int idx = m_base + tid;
    lrow[tid] = rowlist[g * NROWS + (idx < count ? idx : count - 1)];
  }
  __syncthreads();

  const int rr = tid >> 2;            // 0..63
  const int c8 = (tid & 3) << 3;      // k offset (8 elems/thread)
  const float* pa0 = X + (size_t)lrow[rr]      * C_DIM + c8;
  const float* pa1 = X + (size_t)lrow[rr + 64] * C_DIM + c8;
  const float* wbB = Wup + ((size_t)g * TILE_UP + (size_t)nb * 128) * C_DIM;
  const float* pb0 = wbB + (size_t)rr        * C_DIM + c8;
  const float* pb1 = wbB + (size_t)(rr + 64) * C_DIM + c8;

  const int w = tid >> 6, lane = tid & 63;
  const int wm = (w >> 1) << 6, wn = (w & 1) << 6;
  const int fr = lane & 15, fq = lane >> 4;

  const f32x4 zero = {0.f, 0.f, 0.f, 0.f};
  f32x4 acc[4][4];
#pragma unroll
  for (int mi = 0; mi < 4; ++mi)
#pragma unroll
    for (int ni = 0; ni < 4; ++ni) acc[mi][ni] = zero;

  for (int k0 = 0; k0 < C_DIM; k0 += 32) {
    __syncthreads();   // protect LDS reuse from previous iter's readers
    {
      float4 a0 = *(const float4*)(pa0 + k0);
      float4 a1 = *(const float4*)(pa0 + k0 + 4);
      uint4 v; v.x = pk2(a0.x, a0.y); v.y = pk2(a0.z, a0.w);
               v.z = pk2(a1.x, a1.y); v.w = pk2(a1.z, a1.w);
      *(uint4*)&lA[rr * LDA + c8] = v;
      a0 = *(const float4*)(pa1 + k0);
      a1 = *(const float4*)(pa1 + k0 + 4);
      v.x = pk2(a0.x, a0.y); v.y = pk2(a0.z, a0.w);
      v.z = pk2(a1.x, a1.y); v.w = pk2(a1.z, a1.w);
      *(uint4*)&lA[(rr + 64) * LDA + c8] = v;
      float4 b0 = *(const float4*)(pb0 + k0);
      float4 b1 = *(const float4*)(pb0 + k0 + 4);
      v.x = pk2(b0.x, b0.y); v.y = pk2(b0.z, b0.w);
      v.z = pk2(b1.x, b1.y); v.w = pk2(b1.z, b1.w);
      *(uint4*)&lB[rr * LDA + c8] = v;
      b0 = *(const float4*)(pb1 + k0);
      b1 = *(const float4*)(pb1 + k0 + 4);
      v.x = pk2(b0.x, b0.y); v.y = pk2(b0.z, b0.w);
      v.z = pk2(b1.x, b1.y); v.w = pk2(b1.z, b1.w);
      *(uint4*)&lB[(rr + 64) * LDA + c8] = v;
    }
    __syncthreads();
    short8 af[4], bf[4];
#pragma unroll
    for (int mi = 0; mi < 4; ++mi)
      af[mi] = *(const short8*)&lA[(wm + mi * 16 + fr) * LDA + fq * 8];
#pragma unroll
    for (int ni = 0; ni < 4; ++ni)
      bf[ni] = *(const short8*)&lB[(wn + ni * 16 + fr) * LDA + fq * 8];
#pragma unroll
    for (int mi = 0; mi < 4; ++mi)
#pragma unroll
      for (int ni = 0; ni < 4; ++ni)
        acc[mi][ni] = __builtin_amdgcn_mfma_f32_16x16x32_bf16(af[mi], bf[ni], acc[mi][ni], 0, 0, 0);
  }

  // epilogue: C/D layout col=lane&15, row=(lane>>4)*4+reg; hidden row n at u16 idx n*2048
  float bias[4];
#pragma unroll
  for (int ni = 0; ni < 4; ++ni)
    bias[ni] = bup[g * TILE_UP + nb * 128 + wn + ni * 16 + fr];
  const int rb = fq << 2;
#pragma unroll
  for (int mi = 0; mi < 4; ++mi) {
#pragma unroll
    for (int reg = 0; reg < 4; ++reg) {
      int r = wm + mi * 16 + rb + reg;
      if (m_base + r < count) {
        u16* hrow = hid16 + (size_t)lrow[r] * 2048 + nb * 128;
#pragma unroll
        for (int ni = 0; ni < 4; ++ni) {
          float v = acc[mi][ni][reg] + bias[ni];
          v = v > 0.f ? v : 0.f;
          hrow[wn + ni * 16 + fr] = f2bf(v);
        }
      }
    }
  }
}

// grouped GEMM (in-place): out[n, g*256+c] = hid[n,:] @ W_down[g*256+c, g*1024+:]^T + b_down
// + f32 zeros for the 768 non-gated cols. BM=64, BN=256, BK=32; block owns its rows fully.
__global__ void k_down(const float* __restrict__ Wdn, const float* __restrict__ bdn,
                       float* __restrict__ out,
                       const int* __restrict__ cnt, const int* __restrict__ rowlist) {
  const int g = blockIdx.y;
  const int count = cnt[g];
  const int m_base = blockIdx.x << 6;
  if (m_base >= count) return;

  __shared__ __align__(16) u16 lA[64 * LDA];
  __shared__ __align__(16) u16 lB[256 * LDA];
  __shared__ int lrow[64];

  const int tid = threadIdx.x;
  if (tid < 64) {
    int idx = m_base + tid;
    lrow[tid] = rowlist[g * NROWS + (idx < count ? idx : count - 1)];
  }
  __syncthreads();

  const u16* hid16 = (const u16*)out;   // hidden lives bf16 in each out-row's first 2048 B
  const int rr = tid >> 2;              // 0..63
  const int c8 = (tid & 3) << 3;
  const u16* pha = hid16 + (size_t)lrow[rr] * 2048 + c8;
  const float* wbase = Wdn + (size_t)g * TILE_OUT * DFF + (size_t)g * TILE_UP;
  const float* pbg[4];
#pragma unroll
  for (int j = 0; j < 4; ++j)
    pbg[j] = wbase + (size_t)(j * 64 + rr) * DFF + c8;

  const int w = tid >> 6, lane = tid & 63;
  const int wn = w << 6;                // wave col base; all waves share rows 0..63
  const int fr = lane & 15, fq = lane >> 4;

  const f32x4 zero = {0.f, 0.f, 0.f, 0.f};
  f32x4 acc[4][4];
#pragma unroll
  for (int mi = 0; mi < 4; ++mi)
#pragma unroll
    for (int ni = 0; ni < 4; ++ni) acc[mi][ni] = zero;

  for (int k0 = 0; k0 < TILE_UP; k0 += 32) {
    __syncthreads();
    *(uint4*)&lA[rr * LDA + c8] = *(const uint4*)(pha + k0);   // bf16 direct
#pragma unroll
    for (int j = 0; j < 4; ++j) {
      float4 b0 = *(const float4*)(pbg[j] + k0);
      float4 b1 = *(const float4*)(pbg[j] + k0 + 4);
      uint4 v; v.x = pk2(b0.x, b0.y); v.y = pk2(b0.z, b0.w);
               v.z = pk2(b1.x, b1.y); v.w = pk2(b1.z, b1.w);
      *(uint4*)&lB[(j * 64 + rr) * LDA + c8] = v;
    }
    __syncthreads();
    short8 af[4], bf[4];
#pragma unroll
    for (int mi = 0; mi < 4; ++mi)
      af[mi] = *(const short8*)&lA[(mi * 16 + fr) * LDA + fq * 8];
#pragma unroll
    for (int ni = 0; ni < 4; ++ni)
      bf[ni] = *(const short8*)&lB[(wn + ni * 16 + fr) * LDA + fq * 8];
#pragma unroll
    for (int mi = 0; mi < 4; ++mi)
#pragma unroll
      for (int ni = 0; ni < 4; ++ni)
        acc[mi][ni] = __builtin_amdgcn_mfma_f32_16x16x32_bf16(af[mi], bf[ni], acc[mi][ni], 0, 0, 0);
  }
  // ---- all global hidden reads complete before the last mid-loop barrier ----

  // zero the 768 non-gated f32 output columns of our valid rows (4 f32 per store)
  const uint4 z4 = {0u, 0u, 0u, 0u};
  for (int i = tid; i < 64 * 192; i += 256) {
    int r = i / 192, u = i - r * 192;
    if (m_base + r < count) {
      int c = u << 2;
      if (c >= g * TILE_OUT) c += TILE_OUT;
      *(uint4*)(out + (size_t)lrow[r] * C_DIM + c) = z4;
    }
  }

  float bias[4];
#pragma unroll
  for (int ni = 0; ni < 4; ++ni)
    bias[ni] = bdn[g * TILE_OUT + wn + ni * 16 + fr];
  const int rb = fq << 2;
#pragma unroll
  for (int mi = 0; mi < 4; ++mi) {
#pragma unroll
    for (int reg = 0; reg < 4; ++reg) {
      int r = mi * 16 + rb + reg;
      if (m_base + r < count) {
        float* orow = out + (size_t)lrow[r] * C_DIM + g * TILE_OUT;
#pragma unroll
        for (int ni = 0; ni < 4; ++ni)
          orow[wn + ni * 16 + fr] = acc[mi][ni][reg] + bias[ni];
      }
    }
  }
}

extern "C" void kernel_launch(void* const* d_in, const int* in_sizes, int n_in,
                              void* d_out, int out_size, void* d_ws, size_t ws_size,
                              hipStream_t stream) {
  const float* x   = (const float*)d_in[0];
  const float* wg  = (const float*)d_in[1];
  const float* bg  = (const float*)d_in[2];
  const float* wup = (const float*)d_in[3];
  const float* bup = (const float*)d_in[4];
  const float* wdn = (const float*)d_in[5];
  const float* bdn = (const float*)d_in[6];
  float* out      = (float*)d_out;
  float* gate_out = out + (size_t)NROWS * C_DIM;

  char* ws = (char*)d_ws;
  int* cnt     = (int*)ws;             // 4 ints
  int* rowlist = (int*)(ws + 64);      // 4 * 16384 ints = 256 KB total ws use

  k_zero<<<1, 64, 0, stream>>>(cnt);
  k_gate<<<NROWS / 4, 256, 0, stream>>>(x, wg, bg, gate_out, cnt, rowlist);
  // hidden (bf16) is staged into the first 2048 B of each out f32 row (row-aligned alias)
  k_up  <<<dim3(8, 128, 4), 256, 0, stream>>>(x, wup, bup, (u16*)out, cnt, rowlist);
  k_down<<<dim3(256, 4), 256, 0, stream>>>(wdn, bdn, out, cnt, rowlist);
}

// Round 4
// 318.951 us; speedup vs baseline: 1.5864x; 1.5864x over previous
//
#include <hip/hip_runtime.h>
#include <stdint.h>

typedef unsigned short u16;

#define NROWS    16384
#define C_DIM    1024
#define DFF      4096
#define TILE_UP  1024
#define TILE_OUT 256
#define CSTR     16      // counter stride in ints (64 B): one cacheline per gate counter

using short8 = __attribute__((ext_vector_type(8))) short;
using f32x4  = __attribute__((ext_vector_type(4))) float;

// pack two f32 -> two bf16 (RTZ) in one v_perm_b32
__device__ __forceinline__ unsigned pk2(float lo, float hi) {
  union { float f; unsigned u; } L, H; L.f = lo; H.f = hi;
  return __builtin_amdgcn_perm(H.u, L.u, 0x07060302u);
}
// single f32 -> bf16 RNE
__device__ __forceinline__ u16 f2bf(float f) {
  union { float f; unsigned u; } v; v.f = f;
  return (u16)((v.u + 0x7FFFu + ((v.u >> 16) & 1u)) >> 16);
}

// async global->LDS, 16B/lane. Global addr may be per-lane (gather); LDS side is
// wave-uniform base, lane i lands at lp + 16*i.
__device__ __forceinline__ void glds16(const u16* gp, u16* lp) {
  __builtin_amdgcn_global_load_lds((const __attribute__((address_space(1))) void*)gp,
                                   (__attribute__((address_space(3))) void*)lp,
                                   16, 0, 0);
}

__global__ void k_zero(int* __restrict__ cnt) {
  if (threadIdx.x < 4 * CSTR) cnt[threadIdx.x] = 0;
}

// 64 rows/block, wave-per-row x16. Computes gate logits (f32), argmax bucket (LDS-aggregated,
// 4 strided global atomics/block), one-hot gate out, AND converts x rows to bf16 into the
// second half of each f32 out-row (bytes [2048,4096)).
__global__ void k_gate(const float* __restrict__ x, const float* __restrict__ wg,
                       const float* __restrict__ bg, float* __restrict__ gate_out,
                       u16* __restrict__ xb,     // = (u16*)out; row n at xb + n*2048 + 1024
                       int* __restrict__ cnt, int* __restrict__ rowlist) {
  __shared__ int lcnt[4], lbase[4];
  __shared__ unsigned char lgi[64];
  __shared__ unsigned char lpi[64];

  const int tid = threadIdx.x;
  if (tid < 4) lcnt[tid] = 0;
  __syncthreads();

  const int w = tid >> 6, lane = tid & 63;
  for (int i = 0; i < 16; ++i) {
    const int r = (w << 4) + i;                 // row within block
    const int n = (blockIdx.x << 6) + r;
    const float4* xr = (const float4*)(x + (size_t)n * C_DIM);
    u16* xrow = xb + (size_t)n * 2048 + 1024;
    float s0 = 0.f, s1 = 0.f, s2 = 0.f, s3 = 0.f;
#pragma unroll
    for (int it = 0; it < 4; ++it) {
      int c4 = lane + (it << 6);
      float4 xv = xr[c4];
      // bf16 copy of x (8 B/lane, contiguous 512 B per wave-instr)
      uint2 p; p.x = pk2(xv.x, xv.y); p.y = pk2(xv.z, xv.w);
      *(uint2*)(xrow + (c4 << 2)) = p;
      float4 w0 = ((const float4*)(wg + 0 * C_DIM))[c4];
      float4 w1 = ((const float4*)(wg + 1 * C_DIM))[c4];
      float4 w2 = ((const float4*)(wg + 2 * C_DIM))[c4];
      float4 w3 = ((const float4*)(wg + 3 * C_DIM))[c4];
      s0 += xv.x * w0.x + xv.y * w0.y + xv.z * w0.z + xv.w * w0.w;
      s1 += xv.x * w1.x + xv.y * w1.y + xv.z * w1.z + xv.w * w1.w;
      s2 += xv.x * w2.x + xv.y * w2.y + xv.z * w2.z + xv.w * w2.w;
      s3 += xv.x * w3.x + xv.y * w3.y + xv.z * w3.z + xv.w * w3.w;
    }
#pragma unroll
    for (int off = 32; off > 0; off >>= 1) {
      s0 += __shfl_down(s0, off, 64);
      s1 += __shfl_down(s1, off, 64);
      s2 += __shfl_down(s2, off, 64);
      s3 += __shfl_down(s3, off, 64);
    }
    if (lane == 0) {
      float v0 = s0 + bg[0], v1 = s1 + bg[1], v2 = s2 + bg[2], v3 = s3 + bg[3];
      int g = 0; float best = v0;
      if (v1 > best) { best = v1; g = 1; }
      if (v2 > best) { best = v2; g = 2; }
      if (v3 > best) { best = v3; g = 3; }     // strict > == first max, matches np.argmax
      int pos = atomicAdd(&lcnt[g], 1);
      lgi[r] = (unsigned char)g;
      lpi[r] = (unsigned char)pos;
      float4 oh;
      oh.x = (g == 0) ? 1.f : 0.f;
      oh.y = (g == 1) ? 1.f : 0.f;
      oh.z = (g == 2) ? 1.f : 0.f;
      oh.w = (g == 3) ? 1.f : 0.f;
      *(float4*)(gate_out + (size_t)n * 4) = oh;
    }
  }
  __syncthreads();
  if (tid < 4) lbase[tid] = atomicAdd(&cnt[tid * CSTR], lcnt[tid]);
  __syncthreads();
  if (tid < 64) {
    int g = lgi[tid];
    rowlist[g * NROWS + lbase[g] + lpi[tid]] = (blockIdx.x << 6) + tid;
  }
}

// grouped GEMM: hid_bf16[n,0:1024] = relu(x_bf16[n] @ W_up[g*1024+:,:]^T + b_up)
// A (x_bf16, gathered rows) staged via global_load_lds; B (f32 W_up) via pk2 staging.
// 128x128 tile, BK=32, LDA=32, 4 waves.
__global__ void k_up(const u16* __restrict__ xb, const float* __restrict__ Wup,
                     const float* __restrict__ bup, u16* __restrict__ hid16,
                     const int* __restrict__ cnt, const int* __restrict__ rowlist) {
  const int g = blockIdx.z;
  const int count = cnt[g * CSTR];
  const int m_base = blockIdx.y << 7;
  if (m_base >= count) return;
  const int nb = blockIdx.x;  // 0..7

  __shared__ __align__(16) u16 lA[128 * 32];
  __shared__ __align__(16) u16 lB[128 * 32];
  __shared__ int lrow[128];

  const int tid = threadIdx.x;
  if (tid < 128) {
    int idx = m_base + tid;
    lrow[tid] = rowlist[g * NROWS + (idx < count ? idx : count - 1)];
  }
  __syncthreads();

  const int w = tid >> 6, lane = tid & 63;
  // A: wave w stages rows w*16..w*16+15 (and +64); lane covers (row=lane>>2, col=(lane&3)*8)
  const int arow = (w << 4) + (lane >> 2);
  const u16* pa0 = xb + (size_t)lrow[arow]      * 2048 + 1024 + ((lane & 3) << 3);
  const u16* pa1 = xb + (size_t)lrow[arow + 64] * 2048 + 1024 + ((lane & 3) << 3);
  u16* la0 = &lA[(w << 4) * 32];
  u16* la1 = &lA[(64 + (w << 4)) * 32];

  // B: f32 W_up rows, pk2-converted
  const int rr = tid >> 2;
  const int c8 = (tid & 3) << 3;
  const float* wbB = Wup + ((size_t)g * TILE_UP + (size_t)nb * 128) * C_DIM;
  const float* pb0 = wbB + (size_t)rr        * C_DIM + c8;
  const float* pb1 = wbB + (size_t)(rr + 64) * C_DIM + c8;

  const int wm = (w >> 1) << 6, wn = (w & 1) << 6;
  const int fr = lane & 15, fq = lane >> 4;

  const f32x4 zero = {0.f, 0.f, 0.f, 0.f};
  f32x4 acc[4][4];
#pragma unroll
  for (int mi = 0; mi < 4; ++mi)
#pragma unroll
    for (int ni = 0; ni < 4; ++ni) acc[mi][ni] = zero;

  for (int k0 = 0; k0 < C_DIM; k0 += 32) {
    __syncthreads();
    glds16(pa0 + k0, la0);
    glds16(pa1 + k0, la1);
    {
      float4 b0 = *(const float4*)(pb0 + k0);
      float4 b1 = *(const float4*)(pb0 + k0 + 4);
      uint4 v; v.x = pk2(b0.x, b0.y); v.y = pk2(b0.z, b0.w);
               v.z = pk2(b1.x, b1.y); v.w = pk2(b1.z, b1.w);
      *(uint4*)&lB[rr * 32 + c8] = v;
      b0 = *(const float4*)(pb1 + k0);
      b1 = *(const float4*)(pb1 + k0 + 4);
      v.x = pk2(b0.x, b0.y); v.y = pk2(b0.z, b0.w);
      v.z = pk2(b1.x, b1.y); v.w = pk2(b1.z, b1.w);
      *(uint4*)&lB[(rr + 64) * 32 + c8] = v;
    }
    __syncthreads();
    short8 af[4], bf[4];
#pragma unroll
    for (int mi = 0; mi < 4; ++mi)
      af[mi] = *(const short8*)&lA[(wm + mi * 16 + fr) * 32 + fq * 8];
#pragma unroll
    for (int ni = 0; ni < 4; ++ni)
      bf[ni] = *(const short8*)&lB[(wn + ni * 16 + fr) * 32 + fq * 8];
#pragma unroll
    for (int mi = 0; mi < 4; ++mi)
#pragma unroll
      for (int ni = 0; ni < 4; ++ni)
        acc[mi][ni] = __builtin_amdgcn_mfma_f32_16x16x32_bf16(af[mi], bf[ni], acc[mi][ni], 0, 0, 0);
  }

  // epilogue: C/D layout col=lane&15, row=(lane>>4)*4+reg; hidden row n in out-row first half
  float bias[4];
#pragma unroll
  for (int ni = 0; ni < 4; ++ni)
    bias[ni] = bup[g * TILE_UP + nb * 128 + wn + ni * 16 + fr];
  const int rb = fq << 2;
#pragma unroll
  for (int mi = 0; mi < 4; ++mi) {
#pragma unroll
    for (int reg = 0; reg < 4; ++reg) {
      int r = wm + mi * 16 + rb + reg;
      if (m_base + r < count) {
        u16* hrow = hid16 + (size_t)lrow[r] * 2048 + nb * 128;
#pragma unroll
        for (int ni = 0; ni < 4; ++ni) {
          float v = acc[mi][ni][reg] + bias[ni];
          v = v > 0.f ? v : 0.f;
          hrow[wn + ni * 16 + fr] = f2bf(v);
        }
      }
    }
  }
}

// grouped GEMM (in-place): out[n, g*256+c] = hid[n,:] @ W_down[g*256+c, g*1024+:]^T + b_down
// + f32 zeros elsewhere. BM=64, BN=256, BK=32; block owns its rows fully.
// A (hidden bf16, gathered) via global_load_lds; B (f32 W_down) via pk2 staging.
__global__ void k_down(const float* __restrict__ Wdn, const float* __restrict__ bdn,
                       float* __restrict__ out,
                       const int* __restrict__ cnt, const int* __restrict__ rowlist) {
  const int g = blockIdx.y;
  const int count = cnt[g * CSTR];
  const int m_base = blockIdx.x << 6;
  if (m_base >= count) return;

  __shared__ __align__(16) u16 lA[64 * 32];
  __shared__ __align__(16) u16 lB[256 * 32];
  __shared__ int lrow[64];

  const int tid = threadIdx.x;
  if (tid < 64) {
    int idx = m_base + tid;
    lrow[tid] = rowlist[g * NROWS + (idx < count ? idx : count - 1)];
  }
  __syncthreads();

  const u16* hid16 = (const u16*)out;   // hidden bf16 in each out-row's first 2048 B
  const int w = tid >> 6, lane = tid & 63;
  // A: wave w stages rows w*16..w*16+15
  const int arow = (w << 4) + (lane >> 2);
  const u16* pa = hid16 + (size_t)lrow[arow] * 2048 + ((lane & 3) << 3);
  u16* la = &lA[(w << 4) * 32];

  // B: 256 f32 W_down rows, 4 per thread
  const int rr = tid >> 2;
  const int c8 = (tid & 3) << 3;
  const float* wbase = Wdn + (size_t)g * TILE_OUT * DFF + (size_t)g * TILE_UP;
  const float* pbg[4];
#pragma unroll
  for (int j = 0; j < 4; ++j)
    pbg[j] = wbase + (size_t)(j * 64 + rr) * DFF + c8;

  const int wn = w << 6;                // wave col base; all waves share rows 0..63
  const int fr = lane & 15, fq = lane >> 4;

  const f32x4 zero = {0.f, 0.f, 0.f, 0.f};
  f32x4 acc[4][4];
#pragma unroll
  for (int mi = 0; mi < 4; ++mi)
#pragma unroll
    for (int ni = 0; ni < 4; ++ni) acc[mi][ni] = zero;

  for (int k0 = 0; k0 < TILE_UP; k0 += 32) {
    __syncthreads();
    glds16(pa + k0, la);
#pragma unroll
    for (int j = 0; j < 4; ++j) {
      float4 b0 = *(const float4*)(pbg[j] + k0);
      float4 b1 = *(const float4*)(pbg[j] + k0 + 4);
      uint4 v; v.x = pk2(b0.x, b0.y); v.y = pk2(b0.z, b0.w);
               v.z = pk2(b1.x, b1.y); v.w = pk2(b1.z, b1.w);
      *(uint4*)&lB[(j * 64 + rr) * 32 + c8] = v;
    }
    __syncthreads();
    short8 af[4], bf[4];
#pragma unroll
    for (int mi = 0; mi < 4; ++mi)
      af[mi] = *(const short8*)&lA[(mi * 16 + fr) * 32 + fq * 8];
#pragma unroll
    for (int ni = 0; ni < 4; ++ni)
      bf[ni] = *(const short8*)&lB[(wn + ni * 16 + fr) * 32 + fq * 8];
#pragma unroll
    for (int mi = 0; mi < 4; ++mi)
#pragma unroll
      for (int ni = 0; ni < 4; ++ni)
        acc[mi][ni] = __builtin_amdgcn_mfma_f32_16x16x32_bf16(af[mi], bf[ni], acc[mi][ni], 0, 0, 0);
  }
  // ---- all global hidden reads complete at the last mid-loop barrier ----

  // zero the 768 non-gated f32 output columns of our valid rows
  const uint4 z4 = {0u, 0u, 0u, 0u};
  for (int i = tid; i < 64 * 192; i += 256) {
    int r = i / 192, u = i - r * 192;
    if (m_base + r < count) {
      int c = u << 2;
      if (c >= g * TILE_OUT) c += TILE_OUT;
      *(uint4*)(out + (size_t)lrow[r] * C_DIM + c) = z4;
    }
  }

  float bias[4];
#pragma unroll
  for (int ni = 0; ni < 4; ++ni)
    bias[ni] = bdn[g * TILE_OUT + wn + ni * 16 + fr];
  const int rb = fq << 2;
#pragma unroll
  for (int mi = 0; mi < 4; ++mi) {
#pragma unroll
    for (int reg = 0; reg < 4; ++reg) {
      int r = mi * 16 + rb + reg;
      if (m_base + r < count) {
        float* orow = out + (size_t)lrow[r] * C_DIM + g * TILE_OUT;
#pragma unroll
        for (int ni = 0; ni < 4; ++ni)
          orow[wn + ni * 16 + fr] = acc[mi][ni][reg] + bias[ni];
      }
    }
  }
}

extern "C" void kernel_launch(void* const* d_in, const int* in_sizes, int n_in,
                              void* d_out, int out_size, void* d_ws, size_t ws_size,
                              hipStream_t stream) {
  const float* x   = (const float*)d_in[0];
  const float* wg  = (const float*)d_in[1];
  const float* bg  = (const float*)d_in[2];
  const float* wup = (const float*)d_in[3];
  const float* bup = (const float*)d_in[4];
  const float* wdn = (const float*)d_in[5];
  const float* bdn = (const float*)d_in[6];
  float* out      = (float*)d_out;
  float* gate_out = out + (size_t)NROWS * C_DIM;

  char* ws = (char*)d_ws;
  int* cnt     = (int*)ws;              // 4 counters strided 64 B
  int* rowlist = (int*)(ws + 4 * CSTR * sizeof(int) + 192);  // 256 KB

  k_zero<<<1, 64, 0, stream>>>(cnt);
  // x_bf16 -> second half of each out row; hidden bf16 -> first half; final f32 overwrites all
  k_gate<<<NROWS / 64, 256, 0, stream>>>(x, wg, bg, gate_out, (u16*)out, cnt, rowlist);
  k_up  <<<dim3(8, 128, 4), 256, 0, stream>>>((const u16*)out, wup, bup, (u16*)out, cnt, rowlist);
  k_down<<<dim3(256, 4), 256, 0, stream>>>(wdn, bdn, out, cnt, rowlist);
}

// Round 5
// 263.098 us; speedup vs baseline: 1.9232x; 1.2123x over previous
//
#include <hip/hip_runtime.h>
#include <stdint.h>

typedef unsigned short u16;

#define NROWS    16384
#define C_DIM    1024
#define DFF      4096
#define TILE_UP  1024
#define TILE_OUT 256
#define CSTR     16      // counter stride in ints (64 B / cacheline per gate counter)

using short8 = __attribute__((ext_vector_type(8))) short;
using f32x4  = __attribute__((ext_vector_type(4))) float;

// pack two f32 -> two bf16 (RTZ) in one v_perm_b32
__device__ __forceinline__ unsigned pk2(float lo, float hi) {
  union { float f; unsigned u; } L, H; L.f = lo; H.f = hi;
  return __builtin_amdgcn_perm(H.u, L.u, 0x07060302u);
}
// single f32 -> bf16 RNE
__device__ __forceinline__ u16 f2bf(float f) {
  union { float f; unsigned u; } v; v.f = f;
  return (u16)((v.u + 0x7FFFu + ((v.u >> 16) & 1u)) >> 16);
}

// async global->LDS, 16B/lane. Global addr may be per-lane (gather); LDS side is
// wave-uniform base, lane i lands at lp + 16*i.
__device__ __forceinline__ void glds16(const u16* gp, u16* lp) {
  __builtin_amdgcn_global_load_lds((const __attribute__((address_space(1))) void*)gp,
                                   (__attribute__((address_space(3))) void*)lp,
                                   16, 0, 0);
}

// zero counters + convert W_up (full) and W_down (gated slices) to bf16 in ws
__global__ void k_init(const float* __restrict__ Wup, const float* __restrict__ Wdn,
                       u16* __restrict__ wup16, u16* __restrict__ wdn16,
                       int* __restrict__ cnt) {
  const int t = blockIdx.x * 256 + threadIdx.x;
  if (blockIdx.x == 0 && threadIdx.x < 4 * CSTR) cnt[threadIdx.x] = 0;
  if (t < 524288) {                      // W_up: 4096*1024 / 8 per thread
    float4 f0 = ((const float4*)Wup)[t * 2];
    float4 f1 = ((const float4*)Wup)[t * 2 + 1];
    uint4 v; v.x = pk2(f0.x, f0.y); v.y = pk2(f0.z, f0.w);
             v.z = pk2(f1.x, f1.y); v.w = pk2(f1.z, f1.w);
    ((uint4*)wup16)[t] = v;
  } else {                               // W_down gated slices: [4][256][1024] / 8
    int t2 = t - 524288;                 // < 131072
    int e  = t2 << 3;
    int g  = e >> 18, rem = e & 262143;
    int r  = rem >> 10, k = rem & 1023;
    const float* src = Wdn + (size_t)(g * TILE_OUT + r) * DFF + g * TILE_UP + k;
    float4 f0 = *(const float4*)src;
    float4 f1 = *(const float4*)(src + 4);
    uint4 v; v.x = pk2(f0.x, f0.y); v.y = pk2(f0.z, f0.w);
             v.z = pk2(f1.x, f1.y); v.w = pk2(f1.z, f1.w);
    ((uint4*)wdn16)[t2] = v;
  }
}

// 64 rows/block. Gate logits (f32) -> argmax bucket (LDS-aggregated, 4 strided global
// atomics/block), one-hot gate out, AND x->bf16 into the FIRST half of each f32 out-row.
__global__ void k_gate(const float* __restrict__ x, const float* __restrict__ wg,
                       const float* __restrict__ bg, float* __restrict__ gate_out,
                       u16* __restrict__ xb,     // = (u16*)out; row n at xb + n*2048
                       int* __restrict__ cnt, int* __restrict__ rowlist) {
  __shared__ int lcnt[4], lbase[4];
  __shared__ unsigned char lgi[64];
  __shared__ unsigned char lpi[64];

  const int tid = threadIdx.x;
  if (tid < 4) lcnt[tid] = 0;
  __syncthreads();

  const int w = tid >> 6, lane = tid & 63;
  for (int i = 0; i < 16; ++i) {
    const int r = (w << 4) + i;
    const int n = (blockIdx.x << 6) + r;
    const float4* xr = (const float4*)(x + (size_t)n * C_DIM);
    u16* xrow = xb + (size_t)n * 2048;
    float s0 = 0.f, s1 = 0.f, s2 = 0.f, s3 = 0.f;
#pragma unroll
    for (int it = 0; it < 4; ++it) {
      int c4 = lane + (it << 6);
      float4 xv = xr[c4];
      uint2 p; p.x = pk2(xv.x, xv.y); p.y = pk2(xv.z, xv.w);
      *(uint2*)(xrow + (c4 << 2)) = p;
      float4 w0 = ((const float4*)(wg + 0 * C_DIM))[c4];
      float4 w1 = ((const float4*)(wg + 1 * C_DIM))[c4];
      float4 w2 = ((const float4*)(wg + 2 * C_DIM))[c4];
      float4 w3 = ((const float4*)(wg + 3 * C_DIM))[c4];
      s0 += xv.x * w0.x + xv.y * w0.y + xv.z * w0.z + xv.w * w0.w;
      s1 += xv.x * w1.x + xv.y * w1.y + xv.z * w1.z + xv.w * w1.w;
      s2 += xv.x * w2.x + xv.y * w2.y + xv.z * w2.z + xv.w * w2.w;
      s3 += xv.x * w3.x + xv.y * w3.y + xv.z * w3.z + xv.w * w3.w;
    }
#pragma unroll
    for (int off = 32; off > 0; off >>= 1) {
      s0 += __shfl_down(s0, off, 64);
      s1 += __shfl_down(s1, off, 64);
      s2 += __shfl_down(s2, off, 64);
      s3 += __shfl_down(s3, off, 64);
    }
    if (lane == 0) {
      float v0 = s0 + bg[0], v1 = s1 + bg[1], v2 = s2 + bg[2], v3 = s3 + bg[3];
      int g = 0; float best = v0;
      if (v1 > best) { best = v1; g = 1; }
      if (v2 > best) { best = v2; g = 2; }
      if (v3 > best) { best = v3; g = 3; }     // strict > == first max (np.argmax)
      int pos = atomicAdd(&lcnt[g], 1);
      lgi[r] = (unsigned char)g;
      lpi[r] = (unsigned char)pos;
      float4 oh;
      oh.x = (g == 0) ? 1.f : 0.f;
      oh.y = (g == 1) ? 1.f : 0.f;
      oh.z = (g == 2) ? 1.f : 0.f;
      oh.w = (g == 3) ? 1.f : 0.f;
      *(float4*)(gate_out + (size_t)n * 4) = oh;
    }
  }
  __syncthreads();
  if (tid < 4) lbase[tid] = atomicAdd(&cnt[tid * CSTR], lcnt[tid]);
  __syncthreads();
  if (tid < 64) {
    int g = lgi[tid];
    rowlist[g * NROWS + lbase[g] + lpi[tid]] = (blockIdx.x << 6) + tid;
  }
}

// grouped GEMM: hid16[n,0:1024] = relu(x_bf16[n] @ Wup16[g*1024+:,:]^T + b_up)
// All-bf16 K-loop: A (gathered rows, out first half) + B (wup16) via global_load_lds.
// 128x128 tile, BK=32, 4 waves.
__global__ void __launch_bounds__(256, 4)
k_up(const u16* __restrict__ xb, const u16* __restrict__ wup16,
     const float* __restrict__ bup, u16* __restrict__ hid16,
     const int* __restrict__ cnt, const int* __restrict__ rowlist) {
  const int g = blockIdx.z;
  const int count = cnt[g * CSTR];
  const int m_base = blockIdx.y << 7;
  if (m_base >= count) return;
  const int nb = blockIdx.x;  // 0..7

  __shared__ __align__(16) u16 lA[128 * 32];
  __shared__ __align__(16) u16 lB[128 * 32];
  __shared__ int lrow[128];

  const int tid = threadIdx.x;
  if (tid < 128) {
    int idx = m_base + tid;
    lrow[tid] = rowlist[g * NROWS + (idx < count ? idx : count - 1)];
  }
  __syncthreads();

  const int w = tid >> 6, lane = tid & 63;
  const int srow = (w << 4) + (lane >> 2);     // staging row within half-tile
  const int scol = (lane & 3) << 3;            // 8-col chunk
  const u16* pa0 = xb + (size_t)lrow[srow]      * 2048 + scol;   // x_bf16 stride 2048 u16
  const u16* pa1 = xb + (size_t)lrow[srow + 64] * 2048 + scol;
  const u16* wbB = wup16 + ((size_t)g * TILE_UP + (size_t)nb * 128) * C_DIM;
  const u16* pb0 = wbB + (size_t)srow        * C_DIM + scol;
  const u16* pb1 = wbB + (size_t)(srow + 64) * C_DIM + scol;
  u16* la0 = &lA[(w << 4) * 32];       u16* la1 = &lA[(64 + (w << 4)) * 32];
  u16* lb0 = &lB[(w << 4) * 32];       u16* lb1 = &lB[(64 + (w << 4)) * 32];

  const int wm = (w >> 1) << 6, wn = (w & 1) << 6;
  const int fr = lane & 15, fq = lane >> 4;

  const f32x4 zero = {0.f, 0.f, 0.f, 0.f};
  f32x4 acc[4][4];
#pragma unroll
  for (int mi = 0; mi < 4; ++mi)
#pragma unroll
    for (int ni = 0; ni < 4; ++ni) acc[mi][ni] = zero;

  for (int k0 = 0; k0 < C_DIM; k0 += 32) {
    __syncthreads();
    glds16(pa0 + k0, la0); glds16(pa1 + k0, la1);
    glds16(pb0 + k0, lb0); glds16(pb1 + k0, lb1);
    __syncthreads();
    short8 af[4], bf[4];
#pragma unroll
    for (int mi = 0; mi < 4; ++mi)
      af[mi] = *(const short8*)&lA[(wm + mi * 16 + fr) * 32 + fq * 8];
#pragma unroll
    for (int ni = 0; ni < 4; ++ni)
      bf[ni] = *(const short8*)&lB[(wn + ni * 16 + fr) * 32 + fq * 8];
#pragma unroll
    for (int mi = 0; mi < 4; ++mi)
#pragma unroll
      for (int ni = 0; ni < 4; ++ni)
        acc[mi][ni] = __builtin_amdgcn_mfma_f32_16x16x32_bf16(af[mi], bf[ni], acc[mi][ni], 0, 0, 0);
  }

  // epilogue: C/D layout col=lane&15, row=(lane>>4)*4+reg; hid16 row stride 1024 u16
  float bias[4];
#pragma unroll
  for (int ni = 0; ni < 4; ++ni)
    bias[ni] = bup[g * TILE_UP + nb * 128 + wn + ni * 16 + fr];
  const int rb = fq << 2;
#pragma unroll
  for (int mi = 0; mi < 4; ++mi) {
#pragma unroll
    for (int reg = 0; reg < 4; ++reg) {
      int r = wm + mi * 16 + rb + reg;
      if (m_base + r < count) {
        u16* hrow = hid16 + (size_t)lrow[r] * 1024 + nb * 128;
#pragma unroll
        for (int ni = 0; ni < 4; ++ni) {
          float v = acc[mi][ni][reg] + bias[ni];
          v = v > 0.f ? v : 0.f;
          hrow[wn + ni * 16 + fr] = f2bf(v);
        }
      }
    }
  }
}

// grouped GEMM: out[n, g*256 + nb*128 + c] = hid16[n,:] @ wdn16[g][nb*128+c,:]^T + b_down
// BM=64, BN=128, BK=32; 4 waves each 64x32. nb==0 blocks also zero the 768 non-gated cols.
__global__ void __launch_bounds__(256, 2)
k_down(const u16* __restrict__ hid16, const u16* __restrict__ wdn16,
       const float* __restrict__ bdn, float* __restrict__ out,
       const int* __restrict__ cnt, const int* __restrict__ rowlist) {
  const int g = blockIdx.z;
  const int count = cnt[g * CSTR];
  const int m_base = blockIdx.y << 6;
  if (m_base >= count) return;
  const int nb = blockIdx.x;  // 0..1

  __shared__ __align__(16) u16 lA[64 * 32];
  __shared__ __align__(16) u16 lB[128 * 32];
  __shared__ int lrow[64];

  const int tid = threadIdx.x;
  if (tid < 64) {
    int idx = m_base + tid;
    lrow[tid] = rowlist[g * NROWS + (idx < count ? idx : count - 1)];
  }
  __syncthreads();

  const int w = tid >> 6, lane = tid & 63;
  const int srow = (w << 4) + (lane >> 2);
  const int scol = (lane & 3) << 3;
  const u16* pa  = hid16 + (size_t)lrow[srow] * 1024 + scol;
  const u16* wbB = wdn16 + (size_t)(g * TILE_OUT + nb * 128) * TILE_UP;
  const u16* pb0 = wbB + (size_t)srow        * TILE_UP + scol;
  const u16* pb1 = wbB + (size_t)(srow + 64) * TILE_UP + scol;
  u16* la  = &lA[(w << 4) * 32];
  u16* lb0 = &lB[(w << 4) * 32];
  u16* lb1 = &lB[(64 + (w << 4)) * 32];

  const int wn = w << 5;               // wave n-slice (32 cols); rows 0..63 shared
  const int fr = lane & 15, fq = lane >> 4;

  const f32x4 zero = {0.f, 0.f, 0.f, 0.f};
  f32x4 acc[4][2];
#pragma unroll
  for (int mi = 0; mi < 4; ++mi)
#pragma unroll
    for (int ni = 0; ni < 2; ++ni) acc[mi][ni] = zero;

  for (int k0 = 0; k0 < TILE_UP; k0 += 32) {
    __syncthreads();
    glds16(pa + k0, la);
    glds16(pb0 + k0, lb0);
    glds16(pb1 + k0, lb1);
    __syncthreads();
    short8 af[4], bf[2];
#pragma unroll
    for (int mi = 0; mi < 4; ++mi)
      af[mi] = *(const short8*)&lA[(mi * 16 + fr) * 32 + fq * 8];
#pragma unroll
    for (int ni = 0; ni < 2; ++ni)
      bf[ni] = *(const short8*)&lB[(wn + ni * 16 + fr) * 32 + fq * 8];
#pragma unroll
    for (int mi = 0; mi < 4; ++mi)
#pragma unroll
      for (int ni = 0; ni < 2; ++ni)
        acc[mi][ni] = __builtin_amdgcn_mfma_f32_16x16x32_bf16(af[mi], bf[ni], acc[mi][ni], 0, 0, 0);
  }

  // nb==0: zero the 768 non-gated f32 cols of our valid rows (disjoint from gated cols)
  if (nb == 0) {
    const uint4 z4 = {0u, 0u, 0u, 0u};
    for (int i = tid; i < 64 * 192; i += 256) {
      int r = i / 192, u = i - r * 192;
      if (m_base + r < count) {
        int c = u << 2;
        if (c >= g * TILE_OUT) c += TILE_OUT;
        *(uint4*)(out + (size_t)lrow[r] * C_DIM + c) = z4;
      }
    }
  }

  float bias[2];
  const int cb = g * TILE_OUT + nb * 128 + wn;
#pragma unroll
  for (int ni = 0; ni < 2; ++ni)
    bias[ni] = bdn[cb + ni * 16 + fr];
  const int rb = fq << 2;
#pragma unroll
  for (int mi = 0; mi < 4; ++mi) {
#pragma unroll
    for (int reg = 0; reg < 4; ++reg) {
      int r = mi * 16 + rb + reg;
      if (m_base + r < count) {
        float* orow = out + (size_t)lrow[r] * C_DIM + cb;
#pragma unroll
        for (int ni = 0; ni < 2; ++ni)
          orow[ni * 16 + fr] = acc[mi][ni][reg] + bias[ni];
      }
    }
  }
}

extern "C" void kernel_launch(void* const* d_in, const int* in_sizes, int n_in,
                              void* d_out, int out_size, void* d_ws, size_t ws_size,
                              hipStream_t stream) {
  const float* x   = (const float*)d_in[0];
  const float* wg  = (const float*)d_in[1];
  const float* bg  = (const float*)d_in[2];
  const float* wup = (const float*)d_in[3];
  const float* bup = (const float*)d_in[4];
  const float* wdn = (const float*)d_in[5];
  const float* bdn = (const float*)d_in[6];
  float* out      = (float*)d_out;
  float* gate_out = out + (size_t)NROWS * C_DIM;

  char* ws = (char*)d_ws;
  int* cnt     = (int*)ws;                          // 256 B
  int* rowlist = (int*)(ws + 4096);                 // 256 KB
  u16* wup16   = (u16*)(ws + (1u << 20));           // 8 MB  [1 MB, 9 MB)
  u16* wdn16   = (u16*)(ws + 9u * (1u << 20));      // 2 MB  [9 MB, 11 MB)
  u16* hid16   = (u16*)(ws + 16u * (1u << 20));     // 32 MB [16 MB, 48 MB)

  k_init<<<2560, 256, 0, stream>>>(wup, wdn, wup16, wdn16, cnt);
  // x_bf16 -> first half of each out f32 row; final k_down overwrites all of out
  k_gate<<<NROWS / 64, 256, 0, stream>>>(x, wg, bg, gate_out, (u16*)out, cnt, rowlist);
  k_up  <<<dim3(8, 128, 4), 256, 0, stream>>>((const u16*)out, wup16, bup, hid16, cnt, rowlist);
  k_down<<<dim3(2, 256, 4), 256, 0, stream>>>(hid16, wdn16, bdn, out, cnt, rowlist);
}